// Round 6
// baseline (239.790 us; speedup 1.0000x reference)
//
#include <hip/hip_runtime.h>

// Problem constants (from reference)
constexpr int kB   = 128;
constexpr int kU   = 4;
constexpr int kNBS = 64;
constexpr int kS   = 408;
constexpr int kS4  = kS / 4;                               // 102 float4 per row
constexpr unsigned kNQ = (unsigned)kB * kU * kNBS * kS4;   // 3,342,336 float4 groups
constexpr int kChunk   = 4;                                // NBS rows per thread
constexpr unsigned kThreads = kNQ / kChunk;                // 835,584 threads
constexpr float kEmW     = 0.01f;
constexpr float kInvNRad = 1.0f / ((float)kB * kU * kNBS * kS);
constexpr float kInvNAtt = 1.0f / ((float)kB * kU * kS);

// Native clang vector type — required by __builtin_nontemporal_load.
typedef float vfloat4 __attribute__((ext_vector_type(4)));

// R6 mapping: tid in [0, 835584).
//   s4  = tid % 102                    (fastest dim -> coalesced)
//   rem = tid / 102   in [0, 8192)
//   sub = rem % 16, bu = rem / 16      (bu in [0,512) = b*U+u)
//   rows r = bu*64 + sub*4 + j, j=0..3; streaming q_j = r*102 + s4
//   atten a = bu*102 + s4 — loaded once, reused for 4 rows.
// vs R5: chunk 8->4 (2x waves, half the stall phases per thread) and
// __launch_bounds__(256,8) caps VGPR at 64 -> 8 waves/SIMD residency cap.
__global__ void __launch_bounds__(256, 8)
prism_loss_kernel(const vfloat4* __restrict__ atten_re,
                  const vfloat4* __restrict__ atten_im,
                  const vfloat4* __restrict__ rad_re,
                  const vfloat4* __restrict__ rad_im,
                  const vfloat4* __restrict__ tgt_re,
                  const vfloat4* __restrict__ tgt_im,
                  const vfloat4* __restrict__ weights,
                  float* __restrict__ out)
{
    const unsigned tid  = blockIdx.x * 256 + threadIdx.x;   // grid sized exactly
    const unsigned rem  = tid / 102u;                       // magic-mul div
    const unsigned s4   = tid - rem * 102u;
    const unsigned sub  = rem & 15u;
    const unsigned bu   = rem >> 4;
    const unsigned qbase = (bu * 64u + sub * 4u) * 102u + s4;
    const unsigned abase = bu * 102u + s4;
    const bool do_att = (sub == 0u);

    const vfloat4 w  = weights[s4];
    const vfloat4 ar = atten_re[abase];
    const vfloat4 ai = atten_im[abase];

    float recv   = 0.0f;
    float em_rad = 0.0f;
    float em_att = 0.0f;

    // Two batches of 2 rows: 8 NT loads in flight per batch (32 VGPRs data).
    #pragma unroll
    for (int half = 0; half < 2; ++half) {
        vfloat4 rr[2], ri[2], tr[2], ti[2];
        #pragma unroll
        for (int j = 0; j < 2; ++j) {
            const unsigned q = qbase + (unsigned)(half * 2 + j) * 102u;
            rr[j] = __builtin_nontemporal_load(&rad_re[q]);
            ri[j] = __builtin_nontemporal_load(&rad_im[q]);
            tr[j] = __builtin_nontemporal_load(&tgt_re[q]);
            ti[j] = __builtin_nontemporal_load(&tgt_im[q]);
        }
        #pragma unroll
        for (int j = 0; j < 2; ++j) {
            #pragma unroll
            for (int c = 0; c < 4; ++c) {
                const float a_r = ar[c], a_i = ai[c];
                const float r_r = rr[j][c], r_i = ri[j][c];
                const float pr = a_r * r_r - a_i * r_i;
                const float pi = a_r * r_i + a_i * r_r;
                const float dr = pr - tr[j][c];
                const float di = pi - ti[j][c];
                recv = fmaf((dr * dr + di * di), w[c], recv);
                float rm = sqrtf(fmaf(r_r, r_r, r_i * r_i)) - 10.0f;
                rm = fmaxf(rm, 0.0f);
                em_rad = fmaf(rm, rm, em_rad);
            }
        }
    }

    if (do_att) {
        #pragma unroll
        for (int c = 0; c < 4; ++c) {
            float am = sqrtf(fmaf(ar[c], ar[c], ai[c] * ai[c])) - 1.0f;
            am = fmaxf(am, 0.0f);
            em_att = fmaf(am, am, em_att);
        }
    }

    float acc = recv + kEmW * (em_rad * kInvNRad + em_att * kInvNAtt);

    // Wave-64 reduction.
    #pragma unroll
    for (int off = 32; off > 0; off >>= 1)
        acc += __shfl_down(acc, off, 64);

    __shared__ float sdata[4];
    const int lane = threadIdx.x & 63;
    const int wave = threadIdx.x >> 6;
    if (lane == 0) sdata[wave] = acc;
    __syncthreads();
    if (threadIdx.x == 0) {
        atomicAdd(out, sdata[0] + sdata[1] + sdata[2] + sdata[3]);
    }
}

extern "C" void kernel_launch(void* const* d_in, const int* in_sizes, int n_in,
                              void* d_out, int out_size, void* d_ws, size_t ws_size,
                              hipStream_t stream) {
    const vfloat4* atten_re = (const vfloat4*)d_in[0];
    const vfloat4* atten_im = (const vfloat4*)d_in[1];
    const vfloat4* rad_re   = (const vfloat4*)d_in[2];
    const vfloat4* rad_im   = (const vfloat4*)d_in[3];
    const vfloat4* tgt_re   = (const vfloat4*)d_in[4];
    const vfloat4* tgt_im   = (const vfloat4*)d_in[5];
    const vfloat4* weights  = (const vfloat4*)d_in[6];
    float* out = (float*)d_out;

    // d_out is re-poisoned to 0xAA before every timed launch; zero it.
    (void)hipMemsetAsync(out, 0, sizeof(float), stream);

    // 3264 blocks * 256 threads == kThreads exactly (no bounds checks needed).
    prism_loss_kernel<<<(int)(kThreads / 256), 256, 0, stream>>>(
        atten_re, atten_im, rad_re, rad_im, tgt_re, tgt_im, weights, out);
}

// Round 7
// 222.602 us; speedup vs baseline: 1.0772x; 1.0772x over previous
//
#include <hip/hip_runtime.h>

// Problem constants (from reference)
constexpr int kB   = 128;
constexpr int kU   = 4;
constexpr int kNBS = 64;
constexpr int kS   = 408;
constexpr int kS4  = kS / 4;                               // 102 float4 per row
constexpr unsigned kNQ = (unsigned)kB * kU * kNBS * kS4;   // 3,342,336 float4 groups
constexpr int kChunk   = 4;                                // NBS rows per thread
constexpr unsigned kThreads = kNQ / kChunk;                // 835,584 threads
constexpr float kEmW     = 0.01f;
constexpr float kInvNRad = 1.0f / ((float)kB * kU * kNBS * kS);
constexpr float kInvNAtt = 1.0f / ((float)kB * kU * kS);

// Native clang vector type — required by __builtin_nontemporal_load.
typedef float vfloat4 __attribute__((ext_vector_type(4)));

// R7 = R6 mapping WITHOUT the occupancy cap. R6's __launch_bounds__(256,8)
// forced VGPR to 32 -> scratch spills (WRITE_SIZE 51KB -> 91MB, +47MB fetch)
// -> 78us. Natural allocation for this body is ~56-64 VGPR, which reaches
// 8 waves/SIMD on its own without spilling.
//
// Mapping: tid in [0, 835584).
//   s4  = tid % 102                    (fastest dim -> coalesced)
//   rem = tid / 102   in [0, 8192)
//   sub = rem % 16, bu = rem / 16      (bu in [0,512) = b*U+u)
//   rows r = bu*64 + sub*4 + j, j=0..3; streaming q_j = r*102 + s4
//   atten a = bu*102 + s4 — loaded once, reused for 4 rows.
__global__ void __launch_bounds__(256)
prism_loss_kernel(const vfloat4* __restrict__ atten_re,
                  const vfloat4* __restrict__ atten_im,
                  const vfloat4* __restrict__ rad_re,
                  const vfloat4* __restrict__ rad_im,
                  const vfloat4* __restrict__ tgt_re,
                  const vfloat4* __restrict__ tgt_im,
                  const vfloat4* __restrict__ weights,
                  float* __restrict__ out)
{
    const unsigned tid  = blockIdx.x * 256 + threadIdx.x;   // grid sized exactly
    const unsigned rem  = tid / 102u;                       // magic-mul div
    const unsigned s4   = tid - rem * 102u;
    const unsigned sub  = rem & 15u;
    const unsigned bu   = rem >> 4;
    const unsigned qbase = (bu * 64u + sub * 4u) * 102u + s4;
    const unsigned abase = bu * 102u + s4;
    const bool do_att = (sub == 0u);

    const vfloat4 w  = weights[s4];
    const vfloat4 ar = atten_re[abase];
    const vfloat4 ai = atten_im[abase];

    float recv   = 0.0f;
    float em_rad = 0.0f;
    float em_att = 0.0f;

    // Two batches of 2 rows: 8 NT loads in flight per batch (32 VGPRs data).
    #pragma unroll
    for (int half = 0; half < 2; ++half) {
        vfloat4 rr[2], ri[2], tr[2], ti[2];
        #pragma unroll
        for (int j = 0; j < 2; ++j) {
            const unsigned q = qbase + (unsigned)(half * 2 + j) * 102u;
            rr[j] = __builtin_nontemporal_load(&rad_re[q]);
            ri[j] = __builtin_nontemporal_load(&rad_im[q]);
            tr[j] = __builtin_nontemporal_load(&tgt_re[q]);
            ti[j] = __builtin_nontemporal_load(&tgt_im[q]);
        }
        #pragma unroll
        for (int j = 0; j < 2; ++j) {
            #pragma unroll
            for (int c = 0; c < 4; ++c) {
                const float a_r = ar[c], a_i = ai[c];
                const float r_r = rr[j][c], r_i = ri[j][c];
                const float pr = a_r * r_r - a_i * r_i;
                const float pi = a_r * r_i + a_i * r_r;
                const float dr = pr - tr[j][c];
                const float di = pi - ti[j][c];
                recv = fmaf((dr * dr + di * di), w[c], recv);
                float rm = sqrtf(fmaf(r_r, r_r, r_i * r_i)) - 10.0f;
                rm = fmaxf(rm, 0.0f);
                em_rad = fmaf(rm, rm, em_rad);
            }
        }
    }

    if (do_att) {
        #pragma unroll
        for (int c = 0; c < 4; ++c) {
            float am = sqrtf(fmaf(ar[c], ar[c], ai[c] * ai[c])) - 1.0f;
            am = fmaxf(am, 0.0f);
            em_att = fmaf(am, am, em_att);
        }
    }

    float acc = recv + kEmW * (em_rad * kInvNRad + em_att * kInvNAtt);

    // Wave-64 reduction.
    #pragma unroll
    for (int off = 32; off > 0; off >>= 1)
        acc += __shfl_down(acc, off, 64);

    __shared__ float sdata[4];
    const int lane = threadIdx.x & 63;
    const int wave = threadIdx.x >> 6;
    if (lane == 0) sdata[wave] = acc;
    __syncthreads();
    if (threadIdx.x == 0) {
        atomicAdd(out, sdata[0] + sdata[1] + sdata[2] + sdata[3]);
    }
}

extern "C" void kernel_launch(void* const* d_in, const int* in_sizes, int n_in,
                              void* d_out, int out_size, void* d_ws, size_t ws_size,
                              hipStream_t stream) {
    const vfloat4* atten_re = (const vfloat4*)d_in[0];
    const vfloat4* atten_im = (const vfloat4*)d_in[1];
    const vfloat4* rad_re   = (const vfloat4*)d_in[2];
    const vfloat4* rad_im   = (const vfloat4*)d_in[3];
    const vfloat4* tgt_re   = (const vfloat4*)d_in[4];
    const vfloat4* tgt_im   = (const vfloat4*)d_in[5];
    const vfloat4* weights  = (const vfloat4*)d_in[6];
    float* out = (float*)d_out;

    // d_out is re-poisoned to 0xAA before every timed launch; zero it.
    (void)hipMemsetAsync(out, 0, sizeof(float), stream);

    // 3264 blocks * 256 threads == kThreads exactly (no bounds checks needed).
    prism_loss_kernel<<<(int)(kThreads / 256), 256, 0, stream>>>(
        atten_re, atten_im, rad_re, rad_im, tgt_re, tgt_im, weights, out);
}

// Round 8
// 207.867 us; speedup vs baseline: 1.1536x; 1.0709x over previous
//
#include <hip/hip_runtime.h>

// Problem constants (from reference)
constexpr int kB   = 128;
constexpr int kU   = 4;
constexpr int kNBS = 64;
constexpr int kS   = 408;
constexpr int kS4  = kS / 4;                               // 102 float4 per row
constexpr unsigned kNQ = (unsigned)kB * kU * kNBS * kS4;   // 3,342,336 float4 groups
constexpr int kChunk   = 8;                                // NBS rows per thread
constexpr unsigned kThreads = kNQ / kChunk;                // 417,792 threads
constexpr float kEmW     = 0.01f;
constexpr float kInvNRad = 1.0f / ((float)kB * kU * kNBS * kS);
constexpr float kInvNAtt = 1.0f / ((float)kB * kU * kS);

// Native clang vector type — required by __builtin_nontemporal_load.
typedef float vfloat4 __attribute__((ext_vector_type(4)));

// R8: R5's mapping (chunk=8, best so far at 44.5us / 5.3 TB/s aggregate),
// but ALL 32 streaming loads issued as ONE batch (single vmcnt drain-phase
// per thread instead of two). __launch_bounds__(256,3) gives the register
// allocator a 168-VGPR budget so the 128 VGPRs of in-flight load data fit
// WITHOUT spilling (R6 post-mortem: a too-tight cap causes scratch spills,
// visible as WRITE_SIZE in the MB range — watch that counter).
//
// MLP-sweep evidence so far: 8 loads/wave -> 4.3 TB/s, 16 -> 5.3 TB/s.
// This tests 32. If neutral, the per-CU outstanding-miss capacity is the
// hardware ceiling for this single-pass streaming reduction.
//
// Mapping: tid in [0, 417792).
//   s4    = tid % 102                  (fastest dim -> coalesced)
//   rem   = tid / 102   in [0, 4096)
//   chunk = rem % 8, bu = rem / 8      (bu in [0,512) = b*U+u)
//   rows r = bu*64 + chunk*8 + j, j=0..7; streaming q_j = r*102 + s4
//   atten a = bu*102 + s4 — loaded once, reused for all 8 rows.
__global__ void __launch_bounds__(256, 3)
prism_loss_kernel(const vfloat4* __restrict__ atten_re,
                  const vfloat4* __restrict__ atten_im,
                  const vfloat4* __restrict__ rad_re,
                  const vfloat4* __restrict__ rad_im,
                  const vfloat4* __restrict__ tgt_re,
                  const vfloat4* __restrict__ tgt_im,
                  const vfloat4* __restrict__ weights,
                  float* __restrict__ out)
{
    const unsigned tid   = blockIdx.x * 256 + threadIdx.x;  // grid sized exactly
    const unsigned rem   = tid / 102u;                      // magic-mul div
    const unsigned s4    = tid - rem * 102u;
    const unsigned chunk = rem & 7u;
    const unsigned bu    = rem >> 3;
    const unsigned qbase = (bu * 64u + chunk * 8u) * 102u + s4;
    const unsigned abase = bu * 102u + s4;
    const bool do_att = (chunk == 0u);

    const vfloat4 w  = weights[s4];
    const vfloat4 ar = atten_re[abase];
    const vfloat4 ai = atten_im[abase];

    // Single batch: all 32 NT loads issued before any use (128 VGPRs data).
    vfloat4 rr[8], ri[8], tr[8], ti[8];
    #pragma unroll
    for (int j = 0; j < 8; ++j) {
        const unsigned q = qbase + (unsigned)j * 102u;
        rr[j] = __builtin_nontemporal_load(&rad_re[q]);
        ri[j] = __builtin_nontemporal_load(&rad_im[q]);
        tr[j] = __builtin_nontemporal_load(&tgt_re[q]);
        ti[j] = __builtin_nontemporal_load(&tgt_im[q]);
    }

    float recv   = 0.0f;
    float em_rad = 0.0f;
    float em_att = 0.0f;

    // Consume in issue order -> compiler emits incremental vmcnt(N) waits.
    #pragma unroll
    for (int j = 0; j < 8; ++j) {
        #pragma unroll
        for (int c = 0; c < 4; ++c) {
            const float a_r = ar[c], a_i = ai[c];
            const float r_r = rr[j][c], r_i = ri[j][c];
            const float pr = a_r * r_r - a_i * r_i;
            const float pi = a_r * r_i + a_i * r_r;
            const float dr = pr - tr[j][c];
            const float di = pi - ti[j][c];
            recv = fmaf((dr * dr + di * di), w[c], recv);
            float rm = sqrtf(fmaf(r_r, r_r, r_i * r_i)) - 10.0f;
            rm = fmaxf(rm, 0.0f);
            em_rad = fmaf(rm, rm, em_rad);
        }
    }

    if (do_att) {
        #pragma unroll
        for (int c = 0; c < 4; ++c) {
            float am = sqrtf(fmaf(ar[c], ar[c], ai[c] * ai[c])) - 1.0f;
            am = fmaxf(am, 0.0f);
            em_att = fmaf(am, am, em_att);
        }
    }

    float acc = recv + kEmW * (em_rad * kInvNRad + em_att * kInvNAtt);

    // Wave-64 reduction.
    #pragma unroll
    for (int off = 32; off > 0; off >>= 1)
        acc += __shfl_down(acc, off, 64);

    __shared__ float sdata[4];
    const int lane = threadIdx.x & 63;
    const int wave = threadIdx.x >> 6;
    if (lane == 0) sdata[wave] = acc;
    __syncthreads();
    if (threadIdx.x == 0) {
        atomicAdd(out, sdata[0] + sdata[1] + sdata[2] + sdata[3]);
    }
}

extern "C" void kernel_launch(void* const* d_in, const int* in_sizes, int n_in,
                              void* d_out, int out_size, void* d_ws, size_t ws_size,
                              hipStream_t stream) {
    const vfloat4* atten_re = (const vfloat4*)d_in[0];
    const vfloat4* atten_im = (const vfloat4*)d_in[1];
    const vfloat4* rad_re   = (const vfloat4*)d_in[2];
    const vfloat4* rad_im   = (const vfloat4*)d_in[3];
    const vfloat4* tgt_re   = (const vfloat4*)d_in[4];
    const vfloat4* tgt_im   = (const vfloat4*)d_in[5];
    const vfloat4* weights  = (const vfloat4*)d_in[6];
    float* out = (float*)d_out;

    // d_out is re-poisoned to 0xAA before every timed launch; zero it.
    (void)hipMemsetAsync(out, 0, sizeof(float), stream);

    // 1632 blocks * 256 threads == kThreads exactly (no bounds checks needed).
    prism_loss_kernel<<<(int)(kThreads / 256), 256, 0, stream>>>(
        atten_re, atten_im, rad_re, rad_im, tgt_re, tgt_im, weights, out);
}